// Round 1
// 808.050 us; speedup vs baseline: 1.0086x; 1.0086x over previous
//
#include <hip/hip_runtime.h>
#include <stdint.h>

#define IN_F 1024
#define OUT_F 1024
#define INT_DIM 128
#define M_ROWS 16384  // 8 * 2048

#define BM 128
#define BN 128
#define BK 32

typedef float f32x4 __attribute__((ext_vector_type(4)));
typedef __bf16 bf16x8 __attribute__((ext_vector_type(8)));

// round-to-nearest-even fp32 -> bf16 (finite inputs only)
__device__ __forceinline__ unsigned short f2bf(float f) {
  unsigned int u = __float_as_uint(f);
  u += 0x7fffu + ((u >> 16) & 1u);
  return (unsigned short)(u >> 16);
}

// async global->LDS, 16B per lane (wave-uniform base + lane*16 on HW side;
// our LDS layouts are contiguous in lane order so per-lane ptr == base+lane*16)
__device__ __forceinline__ void async_copy16(void* lds_dst, const void* gsrc) {
  __builtin_amdgcn_global_load_lds(
      (const __attribute__((address_space(1))) void*)gsrc,
      (__attribute__((address_space(3))) void*)lds_dst, 16, 0, 0);
}

// ---------------------------------------------------------------------------
// Kernel 1: W_bf16[o*IN_F + i] = sum_d coef[d] * P_w[d][o*IN_F + i]
// 512 MB stream, memory-bound (~82 us floor). One float4 column chunk/thread.
// ---------------------------------------------------------------------------
__global__ void expand_w_kernel(const float* __restrict__ coef,
                                const float* __restrict__ Pw,
                                unsigned short* __restrict__ W) {
  __shared__ float c[INT_DIM];
  if (threadIdx.x < INT_DIM) c[threadIdx.x] = coef[threadIdx.x];
  __syncthreads();
  const int j4 = blockIdx.x * 256 + threadIdx.x;  // 0 .. 262143
  const float4* P4 = (const float4*)Pw;
  float4 acc = make_float4(0.f, 0.f, 0.f, 0.f);
#pragma unroll 8
  for (int d = 0; d < INT_DIM; ++d) {
    float4 p = P4[(size_t)d * (OUT_F * IN_F / 4) + j4];
    float cd = c[d];
    acc.x += cd * p.x;
    acc.y += cd * p.y;
    acc.z += cd * p.z;
    acc.w += cd * p.w;
  }
  union { unsigned short us[4]; uint2 u; } o;
  o.us[0] = f2bf(acc.x);
  o.us[1] = f2bf(acc.y);
  o.us[2] = f2bf(acc.z);
  o.us[3] = f2bf(acc.w);
  ((uint2*)W)[j4] = o.u;
}

// ---------------------------------------------------------------------------
// Kernel 2: bias[o] = sum_d bias_coef[d] * P_b[d][o]   (fp32, tiny)
// ---------------------------------------------------------------------------
__global__ void expand_b_kernel(const float* __restrict__ coef,
                                const float* __restrict__ Pb,
                                float* __restrict__ bias) {
  const int o = blockIdx.x * 256 + threadIdx.x;
  float acc = 0.f;
#pragma unroll 8
  for (int d = 0; d < INT_DIM; ++d) acc += coef[d] * Pb[d * OUT_F + o];
  bias[o] = acc;
}

// ---------------------------------------------------------------------------
// Kernel 3: m97-style bf16 GEMM with FUSED fp32->bf16 A conversion.
// C[m][n] = sum_k A[m][k]*B[n][k] + bias[n]
// A: [M][K] fp32 (x, converted at fragment-load), B: [N][K] bf16, C fp32.
// 128x128 tile, BK=32, 4 waves (2x2), 4x4 16x16x32 MFMA frags per wave.
//
// A is staged as fp32 (16 KB/tile) via global_load_lds. fp32 rows have 128B
// stride -> 16-way bank conflict if linear; we XOR-swizzle the 16B column
// chunk index with (row&7) -- rule 21: linear LDS dest, inverse-swizzled
// GLOBAL source, same XOR on the read address (verified involution; read
// pattern spreads 16 lm-lanes across all 8 bank-groups -> 2-way = free).
//
// Grid is (M/BM, N/BN) so the 8 blocks sharing one A-panel have linear ids
// congruent mod 8 -> same XCD -> A-panel fetched into ONE L2, B (2 MB)
// L2-resident per XCD.
// ---------------------------------------------------------------------------
__global__ __launch_bounds__(256) void gemm_xf32_bt_kernel(
    const float* __restrict__ A,
    const unsigned short* __restrict__ B,
    const float* __restrict__ bias,
    float* __restrict__ C) {
  constexpr int K = IN_F;
  constexpr int N = OUT_F;
  __shared__ float sA[BM * BK];            // 16 KB, fp32, swizzled chunks
  __shared__ unsigned short sB[BN * BK];   // 8 KB, bf16, linear (as m97)

  const int tid = threadIdx.x;
  const int bm = blockIdx.x * BM;   // M on x: same-A blocks share an XCD
  const int bn = blockIdx.y * BN;
  const int lane = tid & 63;
  const int wave = tid >> 6;
  const int wm = (wave >> 1) * 64;
  const int wn = (wave & 1) * 64;
  const int lm = lane & 15;
  const int quad = lane >> 4;

  // A staging: tile = 1024 16B chunks; thread stages 4 (d = tid + 256j).
  // dest chunk d (row rd=d>>3, colchunk cd=d&7) holds global colchunk
  // cd ^ (rd&7)  -> precompute per-thread source row base + swizzled col.
  const float* aSrc[4];
#pragma unroll
  for (int j = 0; j < 4; ++j) {
    const int d = tid + 256 * j;
    const int rd = d >> 3;
    const int cd = d & 7;
    aSrc[j] = A + (size_t)(bm + rd) * K + ((cd ^ (rd & 7)) << 2);
  }

  // B staging: tile = 512 16B chunks; thread stages 2 (unchanged from m97).
  const int q0 = tid;
  const int q1 = tid + 256;
  const int r0 = q0 >> 2, kc0 = (q0 & 3) * 8;
  const int r1 = q1 >> 2, kc1 = (q1 & 3) * 8;

  // A fragment read: row r = wm + f*16 + lm; r&7 == lm&7 (f*16 = 0 mod 8).
  // cols [quad*8, quad*8+8) fp32 = 16B chunks 2q and 2q+1, XOR'd with lm&7.
  const int sw = lm & 7;
  const int co0 = (((quad << 1) | 0) ^ sw) << 2;  // fp32 offset within row
  const int co1 = (((quad << 1) | 1) ^ sw) << 2;

  f32x4 acc[4][4];
  const f32x4 zero = {0.f, 0.f, 0.f, 0.f};
#pragma unroll
  for (int i = 0; i < 4; ++i)
#pragma unroll
    for (int j = 0; j < 4; ++j) acc[i][j] = zero;

  for (int k0 = 0; k0 < K; k0 += BK) {
#pragma unroll
    for (int j = 0; j < 4; ++j)
      async_copy16(&sA[(tid + 256 * j) * 4], aSrc[j] + k0);
    async_copy16(&sB[q0 * 8], &B[(size_t)(bn + r0) * K + k0 + kc0]);
    async_copy16(&sB[q1 * 8], &B[(size_t)(bn + r1) * K + k0 + kc1]);
    __syncthreads();  // drains vmcnt -> staging complete

    bf16x8 af[4], bfr[4];
#pragma unroll
    for (int f = 0; f < 4; ++f) {
      const int rbase = (wm + f * 16 + lm) * BK;
      const f32x4 lo = *(const f32x4*)&sA[rbase + co0];
      const f32x4 hi = *(const f32x4*)&sA[rbase + co1];
      bf16x8 v;
      v[0] = (__bf16)lo[0]; v[1] = (__bf16)lo[1];
      v[2] = (__bf16)lo[2]; v[3] = (__bf16)lo[3];
      v[4] = (__bf16)hi[0]; v[5] = (__bf16)hi[1];
      v[6] = (__bf16)hi[2]; v[7] = (__bf16)hi[3];
      af[f] = v;  // compiler emits v_cvt_pk_bf16_f32 pairs (RTNE)
    }
#pragma unroll
    for (int f = 0; f < 4; ++f)
      bfr[f] = *(const bf16x8*)&sB[(wn + f * 16 + lm) * BK + quad * 8];

#pragma unroll
    for (int fm = 0; fm < 4; ++fm)
#pragma unroll
      for (int fn = 0; fn < 4; ++fn)
        acc[fm][fn] = __builtin_amdgcn_mfma_f32_16x16x32_bf16(
            af[fm], bfr[fn], acc[fm][fn], 0, 0, 0);
    __syncthreads();  // protect LDS from next-iter overwrite
  }

  // epilogue: D layout col=lane&15, row=quad*4+reg (verified m89/m91)
  float bv[4];
#pragma unroll
  for (int fn = 0; fn < 4; ++fn) bv[fn] = bias[bn + wn + fn * 16 + lm];
#pragma unroll
  for (int fm = 0; fm < 4; ++fm) {
#pragma unroll
    for (int r = 0; r < 4; ++r) {
      const int row = bm + wm + fm * 16 + quad * 4 + r;
      float* crow = C + (size_t)row * N + bn + wn + lm;
#pragma unroll
      for (int fn = 0; fn < 4; ++fn) crow[fn * 16] = acc[fm][fn][r] + bv[fn];
    }
  }
}

extern "C" void kernel_launch(void* const* d_in, const int* in_sizes, int n_in,
                              void* d_out, int out_size, void* d_ws,
                              size_t ws_size, hipStream_t stream) {
  const float* x = (const float*)d_in[0];    // [8,2048,1024] fp32
  const float* wc = (const float*)d_in[1];   // [128]
  const float* bc = (const float*)d_in[2];   // [128]
  const float* Pw = (const float*)d_in[3];   // [128, 1048576]
  const float* Pb = (const float*)d_in[4];   // [128, 1024]
  float* out = (float*)d_out;                // [8,2048,1024] fp32

  // workspace layout (needs ~2.1 MB):
  //   [0, 2MB)      W bf16  [1024][1024]
  //   [2MB, 2MB+4K) bias fp32 [1024]
  unsigned short* W = (unsigned short*)d_ws;
  float* bias = (float*)((char*)d_ws + (2u << 20));

  expand_w_kernel<<<OUT_F * IN_F / 4 / 256, 256, 0, stream>>>(wc, Pw, W);
  expand_b_kernel<<<OUT_F / 256, 256, 0, stream>>>(bc, Pb, bias);

  dim3 grid(M_ROWS / BM, OUT_F / BN);  // (128, 8): same-A blocks same XCD
  gemm_xf32_bt_kernel<<<grid, 256, 0, stream>>>(x, W, bias, out);
}

// Round 2
// 804.987 us; speedup vs baseline: 1.0125x; 1.0038x over previous
//
#include <hip/hip_runtime.h>
#include <stdint.h>

#define IN_F 1024
#define OUT_F 1024
#define INT_DIM 128
#define M_ROWS 16384  // 8 * 2048

// GEMM geometry: A (x, fp32) on the 128 side, B (W, bf16) on the 256 side.
#define BM 128
#define BN 256
#define BK 64
#define NT (IN_F / BK)  // 16 K-tiles

typedef float f32x4 __attribute__((ext_vector_type(4)));
typedef __bf16 bf16x8 __attribute__((ext_vector_type(8)));

// round-to-nearest-even fp32 -> bf16 (finite inputs only)
__device__ __forceinline__ unsigned short f2bf(float f) {
  unsigned int u = __float_as_uint(f);
  u += 0x7fffu + ((u >> 16) & 1u);
  return (unsigned short)(u >> 16);
}

// async global->LDS, 16B per lane (wave-uniform base + lane*16 on HW side;
// our LDS layouts are contiguous in lane order so per-lane ptr == base+lane*16)
__device__ __forceinline__ void async_copy16(void* lds_dst, const void* gsrc) {
  __builtin_amdgcn_global_load_lds(
      (const __attribute__((address_space(1))) void*)gsrc,
      (__attribute__((address_space(3))) void*)lds_dst, 16, 0, 0);
}

// ---------------------------------------------------------------------------
// Kernel 1: W_bf16[o*IN_F + i] = sum_d coef[d] * P_w[d][o*IN_F + i]
// 512 MB stream, memory-bound (~82 us floor). One float4 column chunk/thread.
// ---------------------------------------------------------------------------
__global__ void expand_w_kernel(const float* __restrict__ coef,
                                const float* __restrict__ Pw,
                                unsigned short* __restrict__ W) {
  __shared__ float c[INT_DIM];
  if (threadIdx.x < INT_DIM) c[threadIdx.x] = coef[threadIdx.x];
  __syncthreads();
  const int j4 = blockIdx.x * 256 + threadIdx.x;  // 0 .. 262143
  const float4* P4 = (const float4*)Pw;
  float4 acc = make_float4(0.f, 0.f, 0.f, 0.f);
#pragma unroll 8
  for (int d = 0; d < INT_DIM; ++d) {
    float4 p = P4[(size_t)d * (OUT_F * IN_F / 4) + j4];
    float cd = c[d];
    acc.x += cd * p.x;
    acc.y += cd * p.y;
    acc.z += cd * p.z;
    acc.w += cd * p.w;
  }
  union { unsigned short us[4]; uint2 u; } o;
  o.us[0] = f2bf(acc.x);
  o.us[1] = f2bf(acc.y);
  o.us[2] = f2bf(acc.z);
  o.us[3] = f2bf(acc.w);
  ((uint2*)W)[j4] = o.u;
}

// ---------------------------------------------------------------------------
// Kernel 2: bias[o] = sum_d bias_coef[d] * P_b[d][o]   (fp32, tiny)
// ---------------------------------------------------------------------------
__global__ void expand_b_kernel(const float* __restrict__ coef,
                                const float* __restrict__ Pb,
                                float* __restrict__ bias) {
  const int o = blockIdx.x * 256 + threadIdx.x;
  float acc = 0.f;
#pragma unroll 8
  for (int d = 0; d < INT_DIM; ++d) acc += coef[d] * Pb[d * OUT_F + o];
  bias[o] = acc;
}

// ---------------------------------------------------------------------------
// Kernel 3: counted-vmcnt 4-phase pipelined GEMM (T2+T3+T4+T5).
// C[m][n] = sum_k A[m][k]*B[n][k] + bias[n]
// A: [M][K] fp32 (x, converted to bf16 at fragment load), B: [N][K] bf16.
// 128x256 tile, BK=64, 8 waves (2Mx4N), per-wave 64x64 out (4x4 16x16x32).
// LDS 128 KiB: double-buffered A fp32 (2x32K) + B bf16 (2x32K).
//
// Swizzle (rule 21, both-sides): 16B chunk index XOR (row&7), applied to the
// GLOBAL source address at staging (LDS dest stays linear for global_load_lds)
// and to the ds_read address. A-read: balanced over all 8 bank groups (fp32
// rows are 256B; unswizzled would serialize 16 lm-lanes on one group).
// B-read likewise (bf16 rows 128B).
//
// Schedule per tile t (compute buf c, barriers are raw s_barrier in asm —
// NO __syncthreads, so no vmcnt(0) drain):
//   ph1: ds A-qm0 (8xb128) + B-qn0 (4xb128); MFMA q(0,0) x8
//   ph2: ds B-qn1 (4); ISSUE stage B(t+1)->c^1; MFMA q(0,1) x8
//   ph3: ds A-qm1 (8); MFMA q(1,1) x8           [A region of c fully read]
//   ph4: ISSUE stage A(t+2)->c; MFMA q(1,0) x8; s_waitcnt vmcnt(4); barrier
// Steady-state ledger (per-thread, 4 loads per operand-tile): outstanding at
// boundary = A(t+1)[4] + B(t+1)[4] + A(t+2)[4]; vmcnt(4) retires t+1 exactly.
// Every phase barrier carries lgkmcnt(0) so no wave crosses with ds_reads
// outstanding (the staging that follows would clobber the read region).
// ---------------------------------------------------------------------------
__global__ __launch_bounds__(512, 2) void gemm_4ph_kernel(
    const float* __restrict__ A,
    const unsigned short* __restrict__ B,
    const float* __restrict__ bias,
    float* __restrict__ C) {
  constexpr int K = IN_F;
  constexpr int N = OUT_F;
  __shared__ float sA[2][BM * BK];           // 2 x 32 KB fp32
  __shared__ unsigned short sB[2][BN * BK];  // 2 x 32 KB bf16

  const int tid = threadIdx.x;
  const int bid = blockIdx.x;
  const int bm = (bid & 127) * BM;   // A-panel sharers: ids {bm,+128,+256,+384}
  const int bn = (bid >> 7) * BN;    //  -> all same XCD (128%8==0)
  const int lane = tid & 63;
  const int wave = tid >> 6;
  const int wr = wave >> 2;   // 0..1
  const int wc = wave & 3;    // 0..3
  const int lm = lane & 15;
  const int quad = lane >> 4;
  const int sw = lm & 7;

  // ---- staging descriptors (thread stages 4 16B chunks per operand-tile)
  // A: 2048 chunks, 16/row (BK=64 fp32). dest chunk d holds global chunk
  // (d&15)^(row&7) of row d>>4.
  const float *aS0, *aS1, *aS2, *aS3;
  int aD0, aD1, aD2, aD3;
  {
    int d, rd, cd;
    d = tid;            rd = d >> 4; cd = d & 15;
    aS0 = A + (size_t)(bm + rd) * K + ((cd ^ (rd & 7)) << 2); aD0 = d << 2;
    d = tid + 512;      rd = d >> 4; cd = d & 15;
    aS1 = A + (size_t)(bm + rd) * K + ((cd ^ (rd & 7)) << 2); aD1 = d << 2;
    d = tid + 1024;     rd = d >> 4; cd = d & 15;
    aS2 = A + (size_t)(bm + rd) * K + ((cd ^ (rd & 7)) << 2); aD2 = d << 2;
    d = tid + 1536;     rd = d >> 4; cd = d & 15;
    aS3 = A + (size_t)(bm + rd) * K + ((cd ^ (rd & 7)) << 2); aD3 = d << 2;
  }
  // B: 2048 chunks, 8/row (BK=64 bf16).
  const unsigned short *bS0, *bS1, *bS2, *bS3;
  int bD0, bD1, bD2, bD3;
  {
    int d, rd, cd;
    d = tid;            rd = d >> 3; cd = d & 7;
    bS0 = B + (size_t)(bn + rd) * K + ((cd ^ (rd & 7)) << 3); bD0 = d << 3;
    d = tid + 512;      rd = d >> 3; cd = d & 7;
    bS1 = B + (size_t)(bn + rd) * K + ((cd ^ (rd & 7)) << 3); bD1 = d << 3;
    d = tid + 1024;     rd = d >> 3; cd = d & 7;
    bS2 = B + (size_t)(bn + rd) * K + ((cd ^ (rd & 7)) << 3); bD2 = d << 3;
    d = tid + 1536;     rd = d >> 3; cd = d & 7;
    bS3 = B + (size_t)(bn + rd) * K + ((cd ^ (rd & 7)) << 3); bD3 = d << 3;
  }

#define STAGE_A(buf, t)                                \
  do {                                                 \
    async_copy16(&sA[buf][aD0], aS0 + (t) * BK);       \
    async_copy16(&sA[buf][aD1], aS1 + (t) * BK);       \
    async_copy16(&sA[buf][aD2], aS2 + (t) * BK);       \
    async_copy16(&sA[buf][aD3], aS3 + (t) * BK);       \
  } while (0)
#define STAGE_B(buf, t)                                \
  do {                                                 \
    async_copy16(&sB[buf][bD0], bS0 + (t) * BK);       \
    async_copy16(&sB[buf][bD1], bS1 + (t) * BK);       \
    async_copy16(&sB[buf][bD2], bS2 + (t) * BK);       \
    async_copy16(&sB[buf][bD3], bS3 + (t) * BK);       \
  } while (0)

#define PHASE_BAR() \
  asm volatile("s_waitcnt lgkmcnt(0)\n\ts_barrier" ::: "memory")

  // ---- fragment-read offsets (element index), swizzled like staging
  // A frag (fm,kk): row=wr*64+fm*16+lm (row&7==sw), k=kk*32+quad*8(+4)
  int aOff[2][2];
#pragma unroll
  for (int kk = 0; kk < 2; ++kk)
#pragma unroll
    for (int h = 0; h < 2; ++h)
      aOff[kk][h] = ((kk * 8 + quad * 2 + h) ^ sw) << 2;  // fp32 idx
  int bOff[2];
#pragma unroll
  for (int kk = 0; kk < 2; ++kk)
    bOff[kk] = ((kk * 4 + quad) ^ sw) << 3;               // bf16 idx
  int aRow[4], bRow[4];
#pragma unroll
  for (int f = 0; f < 4; ++f) {
    aRow[f] = (wr * 64 + f * 16 + lm) * BK;
    bRow[f] = (wc * 64 + f * 16 + lm) * BK;
  }

  f32x4 acc[4][4];
  const f32x4 zero = {0.f, 0.f, 0.f, 0.f};
#pragma unroll
  for (int i = 0; i < 4; ++i)
#pragma unroll
    for (int j = 0; j < 4; ++j) acc[i][j] = zero;

  bf16x8 af[2][2];   // current A half-frags [fm-local][kk]
  bf16x8 bfr[4][2];  // all B frags for the tile [fn][kk]

#define READ_A(pA, fmBase)                                              \
  do {                                                                  \
    _Pragma("unroll") for (int i = 0; i < 2; ++i) {                     \
      _Pragma("unroll") for (int kk = 0; kk < 2; ++kk) {                \
        f32x4 lo = *(const f32x4*)((pA) + aRow[(fmBase) + i] + aOff[kk][0]); \
        f32x4 hi = *(const f32x4*)((pA) + aRow[(fmBase) + i] + aOff[kk][1]); \
        bf16x8 v;                                                       \
        v[0] = (__bf16)lo[0]; v[1] = (__bf16)lo[1];                     \
        v[2] = (__bf16)lo[2]; v[3] = (__bf16)lo[3];                     \
        v[4] = (__bf16)hi[0]; v[5] = (__bf16)hi[1];                     \
        v[6] = (__bf16)hi[2]; v[7] = (__bf16)hi[3];                     \
        af[i][kk] = v;                                                  \
      }                                                                 \
    }                                                                   \
  } while (0)

#define MFMA_Q(accM, accN)                                              \
  do {                                                                  \
    __builtin_amdgcn_s_setprio(1);                                      \
    _Pragma("unroll") for (int i = 0; i < 2; ++i)                       \
      _Pragma("unroll") for (int j = 0; j < 2; ++j)                     \
        _Pragma("unroll") for (int kk = 0; kk < 2; ++kk)                \
          acc[(accM) + i][(accN) + j] =                                 \
              __builtin_amdgcn_mfma_f32_16x16x32_bf16(                  \
                  af[i][kk], bfr[(accN) + j][kk],                       \
                  acc[(accM) + i][(accN) + j], 0, 0, 0);                \
    __builtin_amdgcn_s_setprio(0);                                      \
  } while (0)

  // ---- prologue: stage A(0),B(0),A(1); wait oldest 8 (= tile 0 complete)
  STAGE_A(0, 0);
  asm volatile("" ::: "memory");
  STAGE_B(0, 0);
  asm volatile("" ::: "memory");
  STAGE_A(1, 1);
  asm volatile("s_waitcnt vmcnt(4)\n\ts_barrier" ::: "memory");

  int cur = 0;
  for (int t = 0; t < NT; ++t) {
    const float* pA = sA[cur];
    const unsigned short* pB = sB[cur];
    const int nxt = cur ^ 1;

    // ---- phase 1: A qm0 + B qn0, MFMA quadrant (0,0)
    READ_A(pA, 0);
#pragma unroll
    for (int j = 0; j < 2; ++j)
#pragma unroll
      for (int kk = 0; kk < 2; ++kk)
        bfr[j][kk] = *(const bf16x8*)(pB + bRow[j] + bOff[kk]);
    MFMA_Q(0, 0);
    PHASE_BAR();

    // ---- phase 2: B qn1; issue B(t+1) -> nxt; MFMA quadrant (0,1)
#pragma unroll
    for (int j = 2; j < 4; ++j)
#pragma unroll
      for (int kk = 0; kk < 2; ++kk)
        bfr[j][kk] = *(const bf16x8*)(pB + bRow[j] + bOff[kk]);
    if (t + 1 < NT) STAGE_B(nxt, t + 1);
    MFMA_Q(0, 2);
    PHASE_BAR();

    // ---- phase 3: A qm1; MFMA quadrant (1,1)
    READ_A(pA, 2);
    MFMA_Q(2, 2);
    PHASE_BAR();  // after this barrier A region of cur is fully consumed

    // ---- phase 4: issue A(t+2) -> cur; MFMA quadrant (1,0); boundary
    if (t + 2 < NT) STAGE_A(cur, t + 2);
    MFMA_Q(2, 0);
    if (t + 1 < NT) {
      if (t + 2 < NT)
        asm volatile("s_waitcnt vmcnt(4) lgkmcnt(0)\n\ts_barrier" ::: "memory");
      else
        asm volatile("s_waitcnt vmcnt(0) lgkmcnt(0)\n\ts_barrier" ::: "memory");
    }
    cur = nxt;
  }

  // ---- epilogue: D layout col=lane&15, row=quad*4+reg (verified m89/m91)
  float bv[4];
#pragma unroll
  for (int fn = 0; fn < 4; ++fn) bv[fn] = bias[bn + wc * 64 + fn * 16 + lm];
#pragma unroll
  for (int fm = 0; fm < 4; ++fm) {
#pragma unroll
    for (int r = 0; r < 4; ++r) {
      const int row = bm + wr * 64 + fm * 16 + quad * 4 + r;
      float* crow = C + (size_t)row * N + bn + wc * 64 + lm;
#pragma unroll
      for (int fn = 0; fn < 4; ++fn) crow[fn * 16] = acc[fm][fn][r] + bv[fn];
    }
  }
#undef STAGE_A
#undef STAGE_B
#undef PHASE_BAR
#undef READ_A
#undef MFMA_Q
}

extern "C" void kernel_launch(void* const* d_in, const int* in_sizes, int n_in,
                              void* d_out, int out_size, void* d_ws,
                              size_t ws_size, hipStream_t stream) {
  const float* x = (const float*)d_in[0];    // [8,2048,1024] fp32
  const float* wc = (const float*)d_in[1];   // [128]
  const float* bc = (const float*)d_in[2];   // [128]
  const float* Pw = (const float*)d_in[3];   // [128, 1048576]
  const float* Pb = (const float*)d_in[4];   // [128, 1024]
  float* out = (float*)d_out;                // [8,2048,1024] fp32

  // workspace layout (needs ~2.1 MB):
  //   [0, 2MB)      W bf16  [1024][1024]
  //   [2MB, 2MB+4K) bias fp32 [1024]
  unsigned short* W = (unsigned short*)d_ws;
  float* bias = (float*)((char*)d_ws + (2u << 20));

  expand_w_kernel<<<OUT_F * IN_F / 4 / 256, 256, 0, stream>>>(wc, Pw, W);
  expand_b_kernel<<<OUT_F / 256, 256, 0, stream>>>(bc, Pb, bias);

  // 1D grid 512: bm-major so the 4 blocks sharing an A-panel land on the
  // same XCD (ids differ by 128 == 0 mod 8).
  gemm_4ph_kernel<<<dim3(512), 512, 0, stream>>>(x, W, bias, out);
}